// Round 5
// baseline (232.181 us; speedup 1.0000x reference)
//
#include <hip/hip_runtime.h>
#include <hip/hip_bf16.h>

typedef short short8 __attribute__((ext_vector_type(8)));
typedef float f32x4 __attribute__((ext_vector_type(4)));

#define MFMA32(a, b, c) __builtin_amdgcn_mfma_f32_16x16x32_bf16(a, b, c, 0, 0, 0)

#if __has_builtin(__builtin_amdgcn_exp2f)
#define EXP2F(x) __builtin_amdgcn_exp2f(x)
#else
#define EXP2F(x) exp2f(x)
#endif

// async global->LDS, 16B per lane; LDS dest = wave-uniform base + lane*16
#define GLL16(gp, lp) __builtin_amdgcn_global_load_lds(                                  \
    (__attribute__((address_space(1))) unsigned int*)(unsigned long long)(const void*)(gp), \
    (__attribute__((address_space(3))) unsigned int*)(lp), 16, 0, 0)

// fp32 -> bf16 RNE
__device__ __forceinline__ unsigned short f2b(float f) {
    union { float f; unsigned int u; } v;
    v.f = f;
    unsigned int u = v.u;
    return (unsigned short)((u + 0x7fffu + ((u >> 16) & 1u)) >> 16);
}

static __device__ __forceinline__ f32x4 max4(f32x4 x, f32x4 y) {
    f32x4 r;
    r[0] = fmaxf(x[0], y[0]); r[1] = fmaxf(x[1], y[1]);
    r[2] = fmaxf(x[2], y[2]); r[3] = fmaxf(x[3], y[3]);
    return r;
}

// ---------------- merged cvt: x (+mask) and 4 weights ----------------
__global__ void cvt_all(const float* __restrict__ x,
                        const float* __restrict__ w0, const float* __restrict__ w1,
                        const float* __restrict__ w2, const float* __restrict__ w3,
                        unsigned short* __restrict__ xb, unsigned short* __restrict__ wb,
                        float* __restrict__ maskbuf) {
    int blk = blockIdx.x;
    if (blk < 4096) {
        int i = blk * 256 + threadIdx.x;           // 0..1048575 float4s
        float4 v = ((const float4*)x)[i];
        ushort4 o;
        o.x = f2b(v.x); o.y = f2b(v.y); o.z = f2b(v.z); o.w = f2b(v.w);
        ((ushort4*)xb)[i] = o;
        if ((i & 255) == 0)
            maskbuf[i >> 8] = (v.x != 0.0f) ? 0.0f : -1e30f;
    } else {
        int wi = blk - 4096;
        int widx = wi >> 10;
        int i = (wi & 1023) * 256 + threadIdx.x;   // 0..262143 float4s
        const float* src = widx == 0 ? w0 : (widx == 1 ? w1 : (widx == 2 ? w2 : w3));
        float4 v = ((const float4*)src)[i];
        ushort4 o;
        o.x = f2b(v.x); o.y = f2b(v.y); o.z = f2b(v.z); o.w = f2b(v.w);
        ((ushort4*)(wb + ((size_t)widx << 20)))[i] = o;
    }
}

// fold softmax scale (Dh^-0.5) and log2(e) into Q so attn uses raw exp2
#define QSCALE (0.125f * 1.44269504088896341f)

// ---------------- fused QKV GEMM, dbuf, operand-swapped epilogues ----------------
// grid (24, 32): seg = blockIdx.x>>3 (0=Q,1=K,2=V).
// Q,K out: (B,H,T,64) bf16, Q pre-scaled. MFMA rows-operand = weights for Q/K
// (lane holds 4 consecutive d -> ushort4 stores), = activations for V.
// V out tiled: [combo][kb128][chunk16][d64][8keys]; key order within each
// 32-group: pos = q*8 + t*4 + i for key 16t+4q+i (PV B-frag order).
__global__ __launch_bounds__(256) void gemm_qkv(
        const unsigned short* __restrict__ A,
        const unsigned short* __restrict__ wq, const unsigned short* __restrict__ wk,
        const unsigned short* __restrict__ wv,
        const float* __restrict__ bq, const float* __restrict__ bk,
        const float* __restrict__ bv,
        unsigned short* __restrict__ qbuf, unsigned short* __restrict__ kbuf,
        unsigned short* __restrict__ vbuf) {
    __shared__ __attribute__((aligned(16))) unsigned short As[2][128 * 32];
    __shared__ __attribute__((aligned(16))) unsigned short Bs[2][128 * 32];
    int tid = threadIdx.x;
    int lane = tid & 63, wave = tid >> 6;
    int lane15 = lane & 15, quad = lane >> 4;
    int seg = blockIdx.x >> 3;
    int bn = (blockIdx.x & 7) * 128;
    int bm = blockIdx.y * 128;
    const unsigned short* Bw = seg == 0 ? wq : (seg == 1 ? wk : wv);
    const float* bias = seg == 0 ? bq : (seg == 1 ? bk : bv);
    int wm = (wave >> 1) * 64, wn = (wave & 1) * 64;

    f32x4 acc[4][4];
#pragma unroll
    for (int i = 0; i < 4; i++)
#pragma unroll
        for (int j = 0; j < 4; j++) acc[i][j] = (f32x4){0.f, 0.f, 0.f, 0.f};

    int arow = tid >> 2, acol = (tid & 3) * 8;
    const unsigned short* A0 = &A[(size_t)(bm + arow) * 1024 + acol];
    const unsigned short* A1 = A0 + (size_t)64 * 1024;
    const unsigned short* B0 = &Bw[(size_t)(bn + arow) * 1024 + acol];
    const unsigned short* B1 = B0 + (size_t)64 * 1024;

    GLL16(A0, &As[0][(size_t)tid * 8]);
    GLL16(A1, &As[0][(size_t)(tid + 256) * 8]);
    GLL16(B0, &Bs[0][(size_t)tid * 8]);
    GLL16(B1, &Bs[0][(size_t)(tid + 256) * 8]);

    // rows-operand (C rows = its index): weights for Q/K, activations for V
    int rb = (seg == 2) ? wm : wn;
    int cb = (seg == 2) ? wn : wm;

    for (int it = 0; it < 32; it++) {
        int cur = it & 1;
        __syncthreads();
        if (it < 31) {
            int kn = (it + 1) * 32;
            GLL16(A0 + kn, &As[cur ^ 1][(size_t)tid * 8]);
            GLL16(A1 + kn, &As[cur ^ 1][(size_t)(tid + 256) * 8]);
            GLL16(B0 + kn, &Bs[cur ^ 1][(size_t)tid * 8]);
            GLL16(B1 + kn, &Bs[cur ^ 1][(size_t)(tid + 256) * 8]);
        }
        const unsigned short* rs = (seg == 2) ? As[cur] : Bs[cur];
        const unsigned short* cs = (seg == 2) ? Bs[cur] : As[cur];
        short8 rf[4], cf[4];
#pragma unroll
        for (int i = 0; i < 4; i++)
            rf[i] = *(const short8*)&rs[(rb + i * 16 + lane15) * 32 + quad * 8];
#pragma unroll
        for (int j = 0; j < 4; j++)
            cf[j] = *(const short8*)&cs[(cb + j * 16 + lane15) * 32 + quad * 8];
#pragma unroll
        for (int i = 0; i < 4; i++)
#pragma unroll
            for (int j = 0; j < 4; j++)
                acc[i][j] = MFMA32(rf[i], cf[j], acc[i][j]);
    }

    int bb = bm >> 11;
    if (seg == 2) {
        // rows = m (t), cols = n (d): lane has 4 consecutive t -> ushort4 along keys
#pragma unroll
        for (int j = 0; j < 4; j++) {
            int nl = bn + wn + j * 16 + lane15;
            int h = nl >> 6, d = nl & 63;
            float bv_ = bias[nl];
            size_t vbase = (size_t)(bb * 16 + h) * 131072;
#pragma unroll
            for (int i = 0; i < 4; i++) {
                int tk0 = (bm & 2047) + wm + i * 16 + quad * 4;
                int B7 = tk0 >> 7, g2 = (tk0 >> 5) & 3;
                ushort4 pk;
                pk.x = f2b(acc[i][j][0] + bv_);
                pk.y = f2b(acc[i][j][1] + bv_);
                pk.z = f2b(acc[i][j][2] + bv_);
                pk.w = f2b(acc[i][j][3] + bv_);
                size_t off = vbase + (size_t)(((B7 * 16 + g2 * 4 + quad) * 64 + d)) * 8
                             + (i & 1) * 4;
                *(ushort4*)&vbuf[off] = pk;
            }
        }
    } else {
        // rows = n (d), cols = m (t): lane has 4 consecutive d -> ushort4 along d
#pragma unroll
        for (int i = 0; i < 4; i++) {
            int n0 = bn + wn + i * 16 + quad * 4;
            int h = n0 >> 6, d0 = n0 & 63;
            f32x4 bv4 = *(const f32x4*)&bias[n0];
            unsigned short* dst = (seg == 0) ? qbuf : kbuf;
#pragma unroll
            for (int j = 0; j < 4; j++) {
                int m = bm + wm + j * 16 + lane15;
                int tk = m & 2047;
                f32x4 v = acc[i][j] + bv4;
                ushort4 pk;
                if (seg == 0) {
                    pk.x = f2b(v[0] * QSCALE); pk.y = f2b(v[1] * QSCALE);
                    pk.z = f2b(v[2] * QSCALE); pk.w = f2b(v[3] * QSCALE);
                } else {
                    pk.x = f2b(v[0]); pk.y = f2b(v[1]);
                    pk.z = f2b(v[2]); pk.w = f2b(v[3]);
                }
                *(ushort4*)&dst[((size_t)((bb * 16 + h) * 2048 + tk)) * 64 + d0] = pk;
            }
        }
    }
}

// ---------------- output projection GEMM: 64x128 tiles, dbuf, float4 stores ----------------
// grid (8, 64). Wave tile 32m x 64n; rows-operand = weights (lane: 4 consecutive n).
__global__ __launch_bounds__(256) void gemm_proj(
        const unsigned short* __restrict__ A, const unsigned short* __restrict__ Bw,
        const float* __restrict__ bias, float* __restrict__ out) {
    __shared__ __attribute__((aligned(16))) unsigned short As[2][64 * 32];
    __shared__ __attribute__((aligned(16))) unsigned short Bs[2][128 * 32];
    int tid = threadIdx.x;
    int lane = tid & 63, wave = tid >> 6;
    int lane15 = lane & 15, quad = lane >> 4;
    int bn = blockIdx.x * 128, bm = blockIdx.y * 64;
    int wm = (wave >> 1) * 32, wn = (wave & 1) * 64;

    f32x4 acc[4][2];
#pragma unroll
    for (int i = 0; i < 4; i++)
#pragma unroll
        for (int j = 0; j < 2; j++) acc[i][j] = (f32x4){0.f, 0.f, 0.f, 0.f};

    int arow = tid >> 2, acol = (tid & 3) * 8;
    const unsigned short* A0 = &A[(size_t)(bm + arow) * 1024 + acol];
    const unsigned short* B0 = &Bw[(size_t)(bn + arow) * 1024 + acol];
    const unsigned short* B1 = B0 + (size_t)64 * 1024;

    GLL16(A0, &As[0][(size_t)tid * 8]);
    GLL16(B0, &Bs[0][(size_t)tid * 8]);
    GLL16(B1, &Bs[0][(size_t)(tid + 256) * 8]);

    for (int it = 0; it < 32; it++) {
        int cur = it & 1;
        __syncthreads();
        if (it < 31) {
            int kn = (it + 1) * 32;
            GLL16(A0 + kn, &As[cur ^ 1][(size_t)tid * 8]);
            GLL16(B0 + kn, &Bs[cur ^ 1][(size_t)tid * 8]);
            GLL16(B1 + kn, &Bs[cur ^ 1][(size_t)(tid + 256) * 8]);
        }
        const unsigned short* as = As[cur];
        const unsigned short* bs = Bs[cur];
        short8 af[2], bf[4];
#pragma unroll
        for (int j = 0; j < 2; j++)
            af[j] = *(const short8*)&as[(wm + j * 16 + lane15) * 32 + quad * 8];
#pragma unroll
        for (int i = 0; i < 4; i++)
            bf[i] = *(const short8*)&bs[(wn + i * 16 + lane15) * 32 + quad * 8];
#pragma unroll
        for (int i = 0; i < 4; i++)
#pragma unroll
            for (int j = 0; j < 2; j++)
                acc[i][j] = MFMA32(bf[i], af[j], acc[i][j]);   // rows = n
    }

#pragma unroll
    for (int i = 0; i < 4; i++) {
        int n0 = bn + wn + i * 16 + quad * 4;
        f32x4 bv4 = *(const f32x4*)&bias[n0];
#pragma unroll
        for (int j = 0; j < 2; j++) {
            int m = bm + wm + j * 16 + lane15;
            f32x4 v = acc[i][j] + bv4;
            *(f32x4*)&out[(size_t)m * 1024 + n0] = v;
        }
    }
}

// ---------------- flash attention v5: K in LDS (dbuf), V register-direct ----------------
// 512 blocks (XCD-swizzled), 4 waves, 32 q/wave. One barrier/iter gating only
// the 16KB K stage. V read per-wave from the tiled vbuf layout into registers
// right after QK — consumed at PV, hidden by softmax, never crosses a barrier.
__global__ __launch_bounds__(256, 2) void attn_kernel(
        const unsigned short* __restrict__ qbuf, const unsigned short* __restrict__ kbuf,
        const unsigned short* __restrict__ vtbuf, const float* __restrict__ maskbuf,
        unsigned short* __restrict__ attnout) {
    __shared__ __attribute__((aligned(16))) unsigned short Ks[2][128 * 64];

    int id = blockIdx.x;
    int combo = (id & 7) | (((id >> 7) & 3) << 3);   // same (b,h) stays on one XCD
    int qt = (id >> 3) & 15;
    int b = combo >> 4, h = combo & 15;
    int tid = threadIdx.x, lane = tid & 63, wave = tid >> 6;
    int lane15 = lane & 15, quad = lane >> 4;
    int q0 = qt * 128 + wave * 32;

    const unsigned short* Q  = qbuf  + (size_t)combo * 2048 * 64;
    const unsigned short* Kp = kbuf  + (size_t)combo * 2048 * 64;
    const unsigned short* Vt = vtbuf + (size_t)combo * 131072;   // tiled
    const float* mb = maskbuf + b * 2048;

    short8 qf[2][2];
#pragma unroll
    for (int a = 0; a < 2; a++)
#pragma unroll
        for (int g = 0; g < 2; g++)
            qf[a][g] = *(const short8*)&Q[(size_t)(q0 + a * 16 + lane15) * 64 + g * 32 + quad * 8];

    float m_run[2] = {-1e30f, -1e30f}, l_run[2] = {0.f, 0.f};
    f32x4 o[2][4];
#pragma unroll
    for (int a = 0; a < 2; a++)
#pragma unroll
        for (int c = 0; c < 4; c++) o[a][c] = (f32x4){0.f, 0.f, 0.f, 0.f};

    const f32x4 z4 = {0.f, 0.f, 0.f, 0.f};
    int x7 = lane15 & 7;

    // prologue: stage K tile 0
#pragma unroll
    for (int r4 = 0; r4 < 4; r4++) {
        int ci = tid + r4 * 256;
        int kr = ci >> 3, kc = (ci & 7) ^ (kr & 7);
        GLL16(&Kp[(size_t)kr * 64 + kc * 8], &Ks[0][(size_t)ci * 8]);
    }

    for (int it = 0; it < 16; it++) {
        int cur = it & 1;
        int kb = it * 128;
        __syncthreads();                       // K[cur] ready; prior reads drained
        if (it < 15) {
#pragma unroll
            for (int r4 = 0; r4 < 4; r4++) {
                int ci = tid + r4 * 256;
                int kr = ci >> 3, kc = (ci & 7) ^ (kr & 7);
                GLL16(&Kp[(size_t)(kb + 128 + kr) * 64 + kc * 8], &Ks[cur ^ 1][(size_t)ci * 8]);
            }
        }
        const unsigned short* ks = Ks[cur];

        // ---- S^T = K.Q^T : 8 key-tiles x 2 q-tiles ----
        f32x4 s[2][8];
#pragma unroll
        for (int t = 0; t < 8; t++) {
            int row = t * 16 + lane15;
            short8 k0 = *(const short8*)&ks[row * 64 + (quad ^ x7) * 8];
            short8 k1 = *(const short8*)&ks[row * 64 + ((quad + 4) ^ x7) * 8];
            f32x4 t0 = MFMA32(k0, qf[0][0], z4);
            s[0][t] = MFMA32(k1, qf[0][1], t0);
            f32x4 t1 = MFMA32(k0, qf[1][0], z4);
            s[1][t] = MFMA32(k1, qf[1][1], t1);
        }

        // ---- V loads for this iter (lane-contiguous tiled layout) ----
        short8 vv[16];
#pragma unroll
        for (int c = 0; c < 4; c++)
#pragma unroll
            for (int g = 0; g < 4; g++)
                vv[c * 4 + g] = *(const short8*)&Vt[
                    (size_t)(((it * 16 + g * 4 + quad) * 64) + c * 16 + lane15) * 8];

        // ---- mask (additive -1e30; scores already in log2 domain) ----
#pragma unroll
        for (int t = 0; t < 8; t++) {
            f32x4 mkt = *(const f32x4*)&mb[kb + t * 16 + quad * 4];
            s[0][t] += mkt;
            s[1][t] += mkt;
        }
        // ---- online softmax + pack P into MFMA32 B-frags ----
        short8 pb8[2][4];
#pragma unroll
        for (int a = 0; a < 2; a++) {
            f32x4 m4 = s[a][0];
#pragma unroll
            for (int t = 1; t < 8; t++) m4 = max4(m4, s[a][t]);
            float mx = fmaxf(fmaxf(m4[0], m4[1]), fmaxf(m4[2], m4[3]));
            mx = fmaxf(mx, __shfl_xor(mx, 16));
            mx = fmaxf(mx, __shfl_xor(mx, 32));
            float mnew = fmaxf(m_run[a], mx);
            float alpha = EXP2F(m_run[a] - mnew);
            m_run[a] = mnew;
            float ls = 0.f;
#pragma unroll
            for (int g = 0; g < 4; g++) {
                float e0 = EXP2F(s[a][2 * g][0] - mnew);
                float e1 = EXP2F(s[a][2 * g][1] - mnew);
                float e2 = EXP2F(s[a][2 * g][2] - mnew);
                float e3 = EXP2F(s[a][2 * g][3] - mnew);
                float f0 = EXP2F(s[a][2 * g + 1][0] - mnew);
                float f1 = EXP2F(s[a][2 * g + 1][1] - mnew);
                float f2 = EXP2F(s[a][2 * g + 1][2] - mnew);
                float f3 = EXP2F(s[a][2 * g + 1][3] - mnew);
                ls += ((e0 + e1) + (e2 + e3)) + ((f0 + f1) + (f2 + f3));
                union { uint4 u; short8 sv; } pu;   // bf16 truncation pack (P in [0,1])
                pu.u.x = __builtin_amdgcn_perm(__float_as_uint(e1), __float_as_uint(e0), 0x07060302u);
                pu.u.y = __builtin_amdgcn_perm(__float_as_uint(e3), __float_as_uint(e2), 0x07060302u);
                pu.u.z = __builtin_amdgcn_perm(__float_as_uint(f1), __float_as_uint(f0), 0x07060302u);
                pu.u.w = __builtin_amdgcn_perm(__float_as_uint(f3), __float_as_uint(f2), 0x07060302u);
                pb8[a][g] = pu.sv;
            }
            l_run[a] = l_run[a] * alpha + ls;
#pragma unroll
            for (int c = 0; c < 4; c++) o[a][c] *= alpha;
        }
        // ---- O^T += V^T.P^T ----
#pragma unroll
        for (int c = 0; c < 4; c++)
#pragma unroll
            for (int g = 0; g < 4; g++) {
                o[0][c] = MFMA32(vv[c * 4 + g], pb8[0][g], o[0][c]);
                o[1][c] = MFMA32(vv[c * 4 + g], pb8[1][g], o[1][c]);
            }
    }

    // ---- epilogue ----
#pragma unroll
    for (int a = 0; a < 2; a++) {
        float l = l_run[a];
        l += __shfl_xor(l, 16);
        l += __shfl_xor(l, 32);
        float rl = 1.0f / l;
        size_t row = (size_t)(b * 2048 + q0 + a * 16 + lane15) * 1024 + h * 64 + quad * 4;
#pragma unroll
        for (int c = 0; c < 4; c++) {
            ushort4 pk;
            pk.x = f2b(o[a][c][0] * rl);
            pk.y = f2b(o[a][c][1] * rl);
            pk.z = f2b(o[a][c][2] * rl);
            pk.w = f2b(o[a][c][3] * rl);
            *(ushort4*)&attnout[row + c * 16] = pk;
        }
    }
}

extern "C" void kernel_launch(void* const* d_in, const int* in_sizes, int n_in,
                              void* d_out, int out_size, void* d_ws, size_t ws_size,
                              hipStream_t stream) {
    const float* x    = (const float*)d_in[0];
    const float* wq_w = (const float*)d_in[1];
    const float* wq_b = (const float*)d_in[2];
    const float* wk_w = (const float*)d_in[3];
    const float* wk_b = (const float*)d_in[4];
    const float* wv_w = (const float*)d_in[5];
    const float* wv_b = (const float*)d_in[6];
    const float* wo_w = (const float*)d_in[7];
    const float* wo_b = (const float*)d_in[8];
    float* out = (float*)d_out;

    char* ws = (char*)d_ws;
    size_t off = 0;
    unsigned short* xb      = (unsigned short*)(ws + off); off += (size_t)4096 * 1024 * 2;
    unsigned short* wb      = (unsigned short*)(ws + off); off += (size_t)4 * 1024 * 1024 * 2;
    unsigned short* qbuf    = (unsigned short*)(ws + off); off += (size_t)4096 * 1024 * 2;
    unsigned short* kbuf    = (unsigned short*)(ws + off); off += (size_t)4096 * 1024 * 2;
    unsigned short* vbuf    = (unsigned short*)(ws + off); off += (size_t)4096 * 1024 * 2;
    unsigned short* attnout = (unsigned short*)(ws + off); off += (size_t)4096 * 1024 * 2;
    float* maskbuf          = (float*)(ws + off);          off += 4096 * 4;

    unsigned short* wqb = wb;
    unsigned short* wkb = wb + (1u << 20);
    unsigned short* wvb = wb + (2u << 20);
    unsigned short* wob = wb + (3u << 20);

    cvt_all<<<8192, 256, 0, stream>>>(x, wq_w, wk_w, wv_w, wo_w, xb, wb, maskbuf);

    gemm_qkv<<<dim3(24, 32), 256, 0, stream>>>(xb, wqb, wkb, wvb,
                                               wq_b, wk_b, wv_b, qbuf, kbuf, vbuf);

    attn_kernel<<<512, 256, 0, stream>>>(qbuf, kbuf, vbuf, maskbuf, attnout);

    gemm_proj<<<dim3(8, 64), 256, 0, stream>>>(attnout, wob, wo_b, out);
}